// Round 13
// baseline (119.001 us; speedup 1.0000x reference)
//
#include <hip/hip_runtime.h>
#include <hip/hip_bf16.h>

typedef __hip_bfloat16 bf16;
typedef __attribute__((ext_vector_type(8))) short bf16x8;
typedef __attribute__((ext_vector_type(4))) float f32x4;
typedef __attribute__((ext_vector_type(4))) unsigned int u32x4;

#define MFMA_BF16(a, b, c) __builtin_amdgcn_mfma_f32_16x16x32_bf16((a), (b), (c), 0, 0, 0)

static constexpr int B_  = 2;
static constexpr int S_  = 2048;
static constexpr int DM_ = 1024;
static constexpr int H_  = 16;
static constexpr int D_  = 64;
static constexpr int M_  = B_ * S_;   // 4096 rows for all GEMMs

__device__ __forceinline__ void load16(const void* g, void* l) {
  __builtin_amdgcn_global_load_lds(
      (const __attribute__((address_space(1))) void*)g,
      (__attribute__((address_space(3))) void*)l, 16, 0, 0);
}

__device__ __forceinline__ unsigned int pack_bf16(float lo, float hi) {
  const unsigned int ul = __builtin_bit_cast(unsigned short, __float2bfloat16(lo));
  const unsigned int uh = __builtin_bit_cast(unsigned short, __float2bfloat16(hi));
  return (uh << 16) | ul;
}

// ---------------- prep kernels ----------------

__global__ void cvt_f32_bf16_kernel(const float* __restrict__ in,
                                    bf16* __restrict__ out, int n4) {
  int i = blockIdx.x * blockDim.x + threadIdx.x;
  if (i >= n4) return;
  float4 v = ((const float4*)in)[i];
  ushort4 u;
  u.x = __builtin_bit_cast(unsigned short, __float2bfloat16(v.x));
  u.y = __builtin_bit_cast(unsigned short, __float2bfloat16(v.y));
  u.z = __builtin_bit_cast(unsigned short, __float2bfloat16(v.z));
  u.w = __builtin_bit_cast(unsigned short, __float2bfloat16(v.w));
  ((ushort4*)out)[i] = u;
}

// out[n][k] = (bf16) in[k][n], 1024x1024 ; blockIdx.z selects which W
__global__ void transpose_cvt_kernel(const float* __restrict__ w0,
                                     const float* __restrict__ w1,
                                     const float* __restrict__ w2,
                                     const float* __restrict__ w3,
                                     bf16* __restrict__ o0, bf16* __restrict__ o1,
                                     bf16* __restrict__ o2, bf16* __restrict__ o3) {
  __shared__ float t[32][33];
  const float* in = blockIdx.z == 0 ? w0 : blockIdx.z == 1 ? w1 : blockIdx.z == 2 ? w2 : w3;
  bf16* out = blockIdx.z == 0 ? o0 : blockIdx.z == 1 ? o1 : blockIdx.z == 2 ? o2 : o3;
  int tx = threadIdx.x & 31;
  int ty = threadIdx.x >> 5;  // 0..7
  int r0 = blockIdx.y * 32;
  int c0 = blockIdx.x * 32;
#pragma unroll
  for (int yy = 0; yy < 32; yy += 8)
    t[ty + yy][tx] = in[(size_t)(r0 + ty + yy) * DM_ + c0 + tx];
  __syncthreads();
#pragma unroll
  for (int yy = 0; yy < 32; yy += 8)
    out[(size_t)(c0 + ty + yy) * DM_ + r0 + tx] = __float2bfloat16(t[tx][ty + yy]);
}

// ---------------- GEMM: C = A(MxK) * Bt(NxK)^T + bias ----------------
// Minimum 2-phase pipeline (T3 recipe): double-buffered LDS, stage(kt+1)
// issued at iter top, counted vmcnt(4) + raw barriers, no vmcnt(0) mid-loop.
// MODE 2: store fp32 to (M, 1024)                 (output projection)
// MODE 3: fused QKV: Bt has 3072 rows (Wq;Wk;Wv). Q,K -> (B,H,S,D) bf16,
//         V -> (B,H,D,S) bf16, at out + proj*4194304 elems.
template <int MODE>
__global__ __launch_bounds__(256) void gemm_bt_kernel(
    const bf16* __restrict__ A, const bf16* __restrict__ Bt,
    const float* __restrict__ bias, const float* __restrict__ bias2,
    const float* __restrict__ bias3, void* __restrict__ out, int K) {
  __shared__ bf16 As[2][128 * 32];
  __shared__ bf16 Bs[2][128 * 32];
  const int tid = threadIdx.x;
  const int wid = tid >> 6, lane = tid & 63;
  const int g = lane >> 4, c = lane & 15;
  const int wr = wid >> 1, wc = wid & 1;  // wave = 64x64 subtile
  const int bm = blockIdx.x, bn = blockIdx.y;

  f32x4 acc[4][4] = {};

  const char* Ag = (const char*)(A + (size_t)bm * 128 * K);
  const char* Bg = (const char*)(Bt + (size_t)bn * 128 * K);
  const int f0 = tid * 16, f1 = f0 + 4096;
  const int r0 = f0 >> 6, cb0 = f0 & 63;
  const int r1 = f1 >> 6;
  const size_t rowbytes = (size_t)K * 2;

  auto stage = [&](int kt, int bufi) {
    const size_t koff = (size_t)kt * 64;  // 32 bf16 = 64B
    load16(Ag + (size_t)r0 * rowbytes + koff + cb0, (char*)As[bufi] + f0);
    load16(Ag + (size_t)r1 * rowbytes + koff + cb0, (char*)As[bufi] + f1);
    load16(Bg + (size_t)r0 * rowbytes + koff + cb0, (char*)Bs[bufi] + f0);
    load16(Bg + (size_t)r1 * rowbytes + koff + cb0, (char*)Bs[bufi] + f1);
  };

  const int NT = K / 32;
  stage(0, 0);
  int cur = 0;
#pragma unroll 1
  for (int kt = 0; kt < NT; ++kt) {
    if (kt + 1 < NT) {
      stage(kt + 1, cur ^ 1);
      asm volatile("s_waitcnt vmcnt(4)" ::: "memory");  // own stage(kt) done
    } else {
      asm volatile("s_waitcnt vmcnt(0)" ::: "memory");
    }
    __builtin_amdgcn_s_barrier();   // all waves' stage(kt) landed

    bf16x8 af[4], bfr[4];
#pragma unroll
    for (int mi = 0; mi < 4; ++mi)
      af[mi] = *(const bf16x8*)&As[cur][(wr * 64 + mi * 16 + c) * 32 + g * 8];
#pragma unroll
    for (int ni = 0; ni < 4; ++ni)
      bfr[ni] = *(const bf16x8*)&Bs[cur][(wc * 64 + ni * 16 + c) * 32 + g * 8];
    __builtin_amdgcn_s_setprio(1);
#pragma unroll
    for (int mi = 0; mi < 4; ++mi)
#pragma unroll
      for (int ni = 0; ni < 4; ++ni)
        acc[mi][ni] = MFMA_BF16(af[mi], bfr[ni], acc[mi][ni]);
    __builtin_amdgcn_s_setprio(0);

    if (kt + 1 < NT) __builtin_amdgcn_s_barrier();  // reads of cur done before
    cur ^= 1;                                       // stage(kt+2) overwrites it
  }

  // epilogue: C row = (lane>>4)*4 + r, col = lane&15  (per 16x16 frag)
#pragma unroll
  for (int ni = 0; ni < 4; ++ni) {
    const int n_g = bn * 128 + wc * 64 + ni * 16 + c;
    float bv;
    if constexpr (MODE == 3) {
      const int proj = n_g >> 10, ncol = n_g & 1023;
      bv = proj == 0 ? bias[ncol] : proj == 1 ? bias2[ncol] : bias3[ncol];
    } else {
      bv = bias[n_g];
    }
#pragma unroll
    for (int mi = 0; mi < 4; ++mi) {
#pragma unroll
      for (int r = 0; r < 4; ++r) {
        const int m_g = bm * 128 + wr * 64 + mi * 16 + g * 4 + r;
        const float val = acc[mi][ni][r] + bv;
        if constexpr (MODE == 2) {
          ((float*)out)[(size_t)m_g * DM_ + n_g] = val;
        } else {
          const int proj = n_g >> 10, ncol = n_g & 1023;
          const int b = m_g >> 11, s = m_g & (S_ - 1);
          const int h = ncol >> 6, d = ncol & (D_ - 1);
          size_t idx = (size_t)proj * 4194304;
          if (proj < 2)
            idx += (((size_t)(b * H_ + h)) * S_ + s) * D_ + d;
          else
            idx += (((size_t)(b * H_ + h)) * D_ + d) * S_ + s;
          ((bf16*)out)[idx] = __float2bfloat16(val);
        }
      }
    }
  }
}

// ---------------- flash attention ----------------
// Q,K: (B,H,S,D) bf16 ; Vt: (B,H,D,S) bf16 ; Aout: (B,S,H*D) bf16
// Block = 4 waves = one t-quad of one bh; double-buffered XOR-swizzled LDS
// (R6-proven __syncthreads pipeline). Swapped-QK^T in-register softmax with
// defer-max gate on the per-lane local max (R10).
// R12 change (only one): l accumulated via an all-ones A-fragment MFMA on
// the idle matrix pipe — D[i][q] = sum_k P^T[k][q] puts the full row denom
// in lacc[0] of every lane; removes the 15-op l-sum tree and the epilogue
// shfl reduce. P->bf16 stays on the proven pack_bf16 (R11's cvt_pk asm was
// the NaN suspect and is dropped per m240's warning).
__global__ __launch_bounds__(256, 4) void flash_attn_kernel(
    const bf16* __restrict__ Q, const bf16* __restrict__ Kg,
    const bf16* __restrict__ Vt, bf16* __restrict__ Aout) {
  __shared__ bf16 Ks[2][64 * 64];
  __shared__ bf16 Vs[2][64 * 64];
  const int tid = threadIdx.x;
  const int w = tid >> 6, lane = tid & 63;
  const int g = lane >> 4, c = lane & 15;

  const int bid = blockIdx.x;
  const int xcd = bid & 7, loc = bid >> 3;
  const int bh = xcd * 4 + (loc & 3);
  const int j = 31 - (loc >> 2);
  const int t = j * 4 + w;
  const int b = bh >> 4, h = bh & (H_ - 1);

  const float ALPHA2 = 0.125f * 1.44269504f;
  const float THR2 = 11.5f;
  const float NEG_INF = -__builtin_inff();

  const char* Kbase = (const char*)(Kg + (size_t)bh * S_ * D_);
  const char* Vbase = (const char*)(Vt + (size_t)bh * D_ * S_);
  const int s0 = tid, s1 = tid + 256;
  const int sr0 = s0 >> 3, sq0 = ((s0 & 7) ^ (sr0 & 7)) << 4;
  const int sr1 = s1 >> 3, sq1 = ((s1 & 7) ^ (sr1 & 7)) << 4;

  const bf16* Qp = Q + ((size_t)bh * S_ + t * 16 + c) * D_;
  bf16x8 qf[2];
  qf[0] = *(const bf16x8*)&Qp[g * 8];
  qf[1] = *(const bf16x8*)&Qp[32 + g * 8];

  // all-ones A-fragment: lacc = mfma(ones, P^T) -> row denom in every lane
  bf16x8 onesf;
#pragma unroll
  for (int jj = 0; jj < 8; ++jj) onesf[jj] = (short)0x3f80;

  f32x4 o[4] = {};
  f32x4 lacc = {};
  float m = -1000.0f;

  const int rowlim = w * 16 + c;
  const int src0 = ((g & 1) * 2) * 16 + c;
  const int src1 = src0 + 16;
  const bool ghi = (g >= 2);
  const int cs = c & 7;
  int roff[2][4];
#pragma unroll
  for (int kk = 0; kk < 2; ++kk)
#pragma unroll
    for (int n = 0; n < 4; ++n)
      roff[kk][n] = n * 2048 + c * 128 + (((kk * 4 + g) ^ cs) << 4);

  {
    load16(Kbase + sr0 * 128 + sq0, (char*)Ks[0] + s0 * 16);
    load16(Kbase + sr1 * 128 + sq1, (char*)Ks[0] + s1 * 16);
    load16(Vbase + sr0 * 4096 + sq0, (char*)Vs[0] + s0 * 16);
    load16(Vbase + sr1 * 4096 + sq1, (char*)Vs[0] + s1 * 16);
  }
  __syncthreads();

  int cur = 0;
#pragma unroll 1
  for (int kv = 0; kv <= j; ++kv) {
    if (kv < j) {
      const char* Krow = Kbase + (size_t)(kv + 1) * 8192;
      const char* Vcol = Vbase + (size_t)(kv + 1) * 128;
      const int nb = cur ^ 1;
      load16(Krow + sr0 * 128 + sq0, (char*)Ks[nb] + s0 * 16);
      load16(Krow + sr1 * 128 + sq1, (char*)Ks[nb] + s1 * 16);
      load16(Vcol + sr0 * 4096 + sq0, (char*)Vs[nb] + s0 * 16);
      load16(Vcol + sr1 * 4096 + sq1, (char*)Vs[nb] + s1 * 16);
    }

    const char* Kt = (const char*)Ks[cur];
    const char* Vtile = (const char*)Vs[cur];
    bf16x8 kf[2][4];
#pragma unroll
    for (int kk = 0; kk < 2; ++kk)
#pragma unroll
      for (int n = 0; n < 4; ++n)
        kf[kk][n] = *(const bf16x8*)(Kt + roff[kk][n]);

    f32x4 st[4] = {};
    __builtin_amdgcn_s_setprio(1);
#pragma unroll
    for (int n = 0; n < 4; ++n) {
      st[n] = MFMA_BF16(kf[0][n], qf[0], st[n]);
      st[n] = MFMA_BF16(kf[1][n], qf[1], st[n]);
    }
    __builtin_amdgcn_s_setprio(0);

    bf16x8 vf[2][4];
#pragma unroll
    for (int kk = 0; kk < 2; ++kk)
#pragma unroll
      for (int n = 0; n < 4; ++n)
        vf[kk][n] = *(const bf16x8*)(Vtile + roff[kk][n]);

    float aa[4][4];
#pragma unroll
    for (int n = 0; n < 4; ++n)
#pragma unroll
      for (int r = 0; r < 4; ++r)
        aa[n][r] = fmaf(st[n][r], ALPHA2, -m);
    if (kv == j) {
#pragma unroll
      for (int n = 0; n < 4; ++n)
#pragma unroll
        for (int r = 0; r < 4; ++r)
          if (n * 16 + g * 4 + r > rowlim) aa[n][r] = NEG_INF;
    }

    // per-lane local max only on the common path; cross-lane + rescale rare
    float lm;
    {
      float t0 = fmaxf(fmaxf(aa[0][0], aa[0][1]), fmaxf(aa[0][2], aa[0][3]));
      float t1 = fmaxf(fmaxf(aa[1][0], aa[1][1]), fmaxf(aa[1][2], aa[1][3]));
      float t2 = fmaxf(fmaxf(aa[2][0], aa[2][1]), fmaxf(aa[2][2], aa[2][3]));
      float t3 = fmaxf(fmaxf(aa[3][0], aa[3][1]), fmaxf(aa[3][2], aa[3][3]));
      lm = fmaxf(fmaxf(t0, t1), fmaxf(t2, t3));
    }

    if (__any(lm > THR2)) {
      float dm = fmaxf(lm, __shfl_xor(lm, 16, 64));
      dm = fmaxf(dm, __shfl_xor(dm, 32, 64));   // row max across g-groups
      const float sh = fmaxf(dm, 0.0f);
      const float sc = __builtin_amdgcn_exp2f(-sh);
      m += sh;
#pragma unroll
      for (int r = 0; r < 4; ++r) lacc[r] *= sc;
#pragma unroll
      for (int n = 0; n < 4; ++n)
#pragma unroll
        for (int r = 0; r < 4; ++r) o[n][r] *= sc;
#pragma unroll
      for (int n = 0; n < 4; ++n)
#pragma unroll
        for (int r = 0; r < 4; ++r) aa[n][r] -= sh;
    }

    float p[4][4];
#pragma unroll
    for (int n = 0; n < 4; ++n)
#pragma unroll
      for (int r = 0; r < 4; ++r) p[n][r] = __builtin_amdgcn_exp2f(aa[n][r]);

    unsigned int dw[4][2];
#pragma unroll
    for (int n = 0; n < 4; ++n) {
      dw[n][0] = pack_bf16(p[n][0], p[n][1]);
      dw[n][1] = pack_bf16(p[n][2], p[n][3]);
    }

#pragma unroll
    for (int kk = 0; kk < 2; ++kk) {
      unsigned int bb[4];
      {
        unsigned int lo = __shfl(dw[kk * 2][0], src0, 64);
        unsigned int hi = __shfl(dw[kk * 2 + 1][0], src0, 64);
        bb[0] = ghi ? hi : lo;
      }
      {
        unsigned int lo = __shfl(dw[kk * 2][1], src0, 64);
        unsigned int hi = __shfl(dw[kk * 2 + 1][1], src0, 64);
        bb[1] = ghi ? hi : lo;
      }
      {
        unsigned int lo = __shfl(dw[kk * 2][0], src1, 64);
        unsigned int hi = __shfl(dw[kk * 2 + 1][0], src1, 64);
        bb[2] = ghi ? hi : lo;
      }
      {
        unsigned int lo = __shfl(dw[kk * 2][1], src1, 64);
        unsigned int hi = __shfl(dw[kk * 2 + 1][1], src1, 64);
        bb[3] = ghi ? hi : lo;
      }
      u32x4 bbv = {bb[0], bb[1], bb[2], bb[3]};
      bf16x8 pb = __builtin_bit_cast(bf16x8, bbv);
      __builtin_amdgcn_s_setprio(1);
#pragma unroll
      for (int n = 0; n < 4; ++n) o[n] = MFMA_BF16(vf[kk][n], pb, o[n]);
      lacc = MFMA_BF16(onesf, pb, lacc);   // row denom, all lanes, lacc[0]
      __builtin_amdgcn_s_setprio(0);
    }

    __syncthreads();
    cur ^= 1;
  }

  const float inv = 1.0f / lacc[0];

  bf16* Arow = Aout + ((size_t)b * S_ + t * 16 + c) * (H_ * D_) + h * D_;
#pragma unroll
  for (int n = 0; n < 4; ++n) {
    ushort4 u;
    u.x = __builtin_bit_cast(unsigned short, __float2bfloat16(o[n][0] * inv));
    u.y = __builtin_bit_cast(unsigned short, __float2bfloat16(o[n][1] * inv));
    u.z = __builtin_bit_cast(unsigned short, __float2bfloat16(o[n][2] * inv));
    u.w = __builtin_bit_cast(unsigned short, __float2bfloat16(o[n][3] * inv));
    *(ushort4*)&Arow[n * 16 + g * 4] = u;
  }
}

// ---------------- launcher ----------------

extern "C" void kernel_launch(void* const* d_in, const int* in_sizes, int n_in,
                              void* d_out, int out_size, void* d_ws, size_t ws_size,
                              hipStream_t stream) {
  (void)in_sizes; (void)n_in; (void)out_size; (void)ws_size;
  const float* x  = (const float*)d_in[0];
  const float* Wq = (const float*)d_in[1];
  const float* bq = (const float*)d_in[2];
  const float* Wk = (const float*)d_in[3];
  const float* bk = (const float*)d_in[4];
  const float* Wv = (const float*)d_in[5];
  const float* bv = (const float*)d_in[6];
  const float* Wo = (const float*)d_in[7];
  const float* bo = (const float*)d_in[8];
  float* out = (float*)d_out;

  char* ws = (char*)d_ws;
  bf16* xb  = (bf16*)(ws);                    // 8 MB  (4096x1024 bf16)
  bf16* Wqt = (bf16*)(ws + (8u << 20));       // 2 MB each, CONTIGUOUS (QKV fused)
  bf16* Wkt = (bf16*)(ws + (10u << 20));
  bf16* Wvt = (bf16*)(ws + (12u << 20));
  bf16* Wot = (bf16*)(ws + (14u << 20));
  bf16* Qb  = (bf16*)(ws + (16u << 20));      // 8 MB  (B,H,S,D)  -- +0*4194304
  bf16* Kb  = (bf16*)(ws + (24u << 20));      // 8 MB             -- +1*4194304
  bf16* Vtb = (bf16*)(ws + (32u << 20));      // 8 MB  (B,H,D,S)  -- +2*4194304
  bf16* Ab  = xb;  // attention out reuses xb (xb dead after projections)

  cvt_f32_bf16_kernel<<<4096, 256, 0, stream>>>(x, xb, (M_ * DM_) / 4);
  transpose_cvt_kernel<<<dim3(32, 32, 4), 256, 0, stream>>>(
      Wq, Wk, Wv, Wo, Wqt, Wkt, Wvt, Wot);

  // fused QKV projection: Bt = [Wqt;Wkt;Wvt] (3072 rows), 2-phase 128^2
  gemm_bt_kernel<3><<<dim3(32, 24), 256, 0, stream>>>(
      xb, Wqt, bq, bk, bv, (void*)Qb, DM_);

  flash_attn_kernel<<<dim3(1024), 256, 0, stream>>>(Qb, Kb, Vtb, Ab);

  gemm_bt_kernel<2><<<dim3(32, 8), 256, 0, stream>>>(
      Ab, Wot, bo, nullptr, nullptr, (void*)out, DM_);
}

// Round 14
// 113.059 us; speedup vs baseline: 1.0526x; 1.0526x over previous
//
#include <hip/hip_runtime.h>
#include <hip/hip_bf16.h>

typedef __hip_bfloat16 bf16;
typedef __attribute__((ext_vector_type(8))) short bf16x8;
typedef __attribute__((ext_vector_type(4))) float f32x4;
typedef __attribute__((ext_vector_type(4))) unsigned int u32x4;

#define MFMA_BF16(a, b, c) __builtin_amdgcn_mfma_f32_16x16x32_bf16((a), (b), (c), 0, 0, 0)

static constexpr int B_  = 2;
static constexpr int S_  = 2048;
static constexpr int DM_ = 1024;
static constexpr int H_  = 16;
static constexpr int D_  = 64;
static constexpr int M_  = B_ * S_;   // 4096 rows for all GEMMs

__device__ __forceinline__ void load16(const void* g, void* l) {
  __builtin_amdgcn_global_load_lds(
      (const __attribute__((address_space(1))) void*)g,
      (__attribute__((address_space(3))) void*)l, 16, 0, 0);
}

__device__ __forceinline__ unsigned int pack_bf16(float lo, float hi) {
  const unsigned int ul = __builtin_bit_cast(unsigned short, __float2bfloat16(lo));
  const unsigned int uh = __builtin_bit_cast(unsigned short, __float2bfloat16(hi));
  return (uh << 16) | ul;
}

// ---------------- fused prep: 4x weight transpose + x cvt ----------------
// z<4: out[n][k] = (bf16) W[k][n]; z==4: xb = (bf16) x (4M elems)
__global__ void prep_kernel(const float* __restrict__ w0,
                            const float* __restrict__ w1,
                            const float* __restrict__ w2,
                            const float* __restrict__ w3,
                            const float* __restrict__ x,
                            bf16* __restrict__ o0, bf16* __restrict__ o1,
                            bf16* __restrict__ o2, bf16* __restrict__ o3,
                            bf16* __restrict__ xb) {
  if (blockIdx.z == 4) {
    const int blk = blockIdx.y * 32 + blockIdx.x;   // 0..1023
#pragma unroll
    for (int rep = 0; rep < 4; ++rep) {
      const int i = blk * 1024 + rep * 256 + threadIdx.x;  // float4 index
      float4 v = ((const float4*)x)[i];
      ushort4 u;
      u.x = __builtin_bit_cast(unsigned short, __float2bfloat16(v.x));
      u.y = __builtin_bit_cast(unsigned short, __float2bfloat16(v.y));
      u.z = __builtin_bit_cast(unsigned short, __float2bfloat16(v.z));
      u.w = __builtin_bit_cast(unsigned short, __float2bfloat16(v.w));
      ((ushort4*)xb)[i] = u;
    }
    return;
  }
  __shared__ float t[32][33];
  const float* in = blockIdx.z == 0 ? w0 : blockIdx.z == 1 ? w1 : blockIdx.z == 2 ? w2 : w3;
  bf16* out = blockIdx.z == 0 ? o0 : blockIdx.z == 1 ? o1 : blockIdx.z == 2 ? o2 : o3;
  int tx = threadIdx.x & 31;
  int ty = threadIdx.x >> 5;  // 0..7
  int r0 = blockIdx.y * 32;
  int c0 = blockIdx.x * 32;
#pragma unroll
  for (int yy = 0; yy < 32; yy += 8)
    t[ty + yy][tx] = in[(size_t)(r0 + ty + yy) * DM_ + c0 + tx];
  __syncthreads();
#pragma unroll
  for (int yy = 0; yy < 32; yy += 8)
    out[(size_t)(c0 + ty + yy) * DM_ + r0 + tx] = __float2bfloat16(t[tx][ty + yy]);
}

// ---------------- QKV GEMM (2-phase, 128x128, proven) ----------------
// Bt has 3072 rows (Wq;Wk;Wv). Q,K -> (B,H,S,D) bf16, V -> (B,H,D,S) bf16.
__global__ __launch_bounds__(256) void gemm_qkv_kernel(
    const bf16* __restrict__ A, const bf16* __restrict__ Bt,
    const float* __restrict__ bias, const float* __restrict__ bias2,
    const float* __restrict__ bias3, bf16* __restrict__ out, int K) {
  __shared__ bf16 As[2][128 * 32];
  __shared__ bf16 Bs[2][128 * 32];
  const int tid = threadIdx.x;
  const int wid = tid >> 6, lane = tid & 63;
  const int g = lane >> 4, c = lane & 15;
  const int wr = wid >> 1, wc = wid & 1;  // wave = 64x64 subtile
  const int bm = blockIdx.x, bn = blockIdx.y;

  f32x4 acc[4][4] = {};

  const char* Ag = (const char*)(A + (size_t)bm * 128 * K);
  const char* Bg = (const char*)(Bt + (size_t)bn * 128 * K);
  const int f0 = tid * 16, f1 = f0 + 4096;
  const int r0 = f0 >> 6, cb0 = f0 & 63;
  const int r1 = f1 >> 6;
  const size_t rowbytes = (size_t)K * 2;

  auto stage = [&](int kt, int bufi) {
    const size_t koff = (size_t)kt * 64;  // 32 bf16 = 64B
    load16(Ag + (size_t)r0 * rowbytes + koff + cb0, (char*)As[bufi] + f0);
    load16(Ag + (size_t)r1 * rowbytes + koff + cb0, (char*)As[bufi] + f1);
    load16(Bg + (size_t)r0 * rowbytes + koff + cb0, (char*)Bs[bufi] + f0);
    load16(Bg + (size_t)r1 * rowbytes + koff + cb0, (char*)Bs[bufi] + f1);
  };

  const int NT = K / 32;
  stage(0, 0);
  int cur = 0;
#pragma unroll 1
  for (int kt = 0; kt < NT; ++kt) {
    if (kt + 1 < NT) {
      stage(kt + 1, cur ^ 1);
      asm volatile("s_waitcnt vmcnt(4)" ::: "memory");  // own stage(kt) done
    } else {
      asm volatile("s_waitcnt vmcnt(0)" ::: "memory");
    }
    __builtin_amdgcn_s_barrier();   // all waves' stage(kt) landed

    bf16x8 af[4], bfr[4];
#pragma unroll
    for (int mi = 0; mi < 4; ++mi)
      af[mi] = *(const bf16x8*)&As[cur][(wr * 64 + mi * 16 + c) * 32 + g * 8];
#pragma unroll
    for (int ni = 0; ni < 4; ++ni)
      bfr[ni] = *(const bf16x8*)&Bs[cur][(wc * 64 + ni * 16 + c) * 32 + g * 8];
    __builtin_amdgcn_s_setprio(1);
#pragma unroll
    for (int mi = 0; mi < 4; ++mi)
#pragma unroll
      for (int ni = 0; ni < 4; ++ni)
        acc[mi][ni] = MFMA_BF16(af[mi], bfr[ni], acc[mi][ni]);
    __builtin_amdgcn_s_setprio(0);

    if (kt + 1 < NT) __builtin_amdgcn_s_barrier();  // reads of cur done before
    cur ^= 1;                                       // stage(kt+2) overwrites it
  }

#pragma unroll
  for (int ni = 0; ni < 4; ++ni) {
    const int n_g = bn * 128 + wc * 64 + ni * 16 + c;
    const int proj = n_g >> 10, ncol = n_g & 1023;
    const float bv = proj == 0 ? bias[ncol] : proj == 1 ? bias2[ncol] : bias3[ncol];
    const int h = ncol >> 6, d = ncol & (D_ - 1);
#pragma unroll
    for (int mi = 0; mi < 4; ++mi) {
#pragma unroll
      for (int r = 0; r < 4; ++r) {
        const int m_g = bm * 128 + wr * 64 + mi * 16 + g * 4 + r;
        const float val = acc[mi][ni][r] + bv;
        const int b = m_g >> 11, s = m_g & (S_ - 1);
        size_t idx = (size_t)proj * 4194304;
        if (proj < 2)
          idx += (((size_t)(b * H_ + h)) * S_ + s) * D_ + d;
        else
          idx += (((size_t)(b * H_ + h)) * D_ + d) * S_ + s;
        out[idx] = __float2bfloat16(val);
      }
    }
  }
}

// ---------------- output projection GEMM (2-phase, 128x64 tile) ----------
// 512 blocks = 2/CU so barrier stalls overlap across blocks. fp32 out.
__global__ __launch_bounds__(256) void gemm_out_kernel(
    const bf16* __restrict__ A, const bf16* __restrict__ Bt,
    const float* __restrict__ bias, float* __restrict__ out, int K) {
  __shared__ bf16 As[2][128 * 32];
  __shared__ bf16 Bs[2][64 * 32];
  const int tid = threadIdx.x;
  const int wid = tid >> 6, lane = tid & 63;
  const int g = lane >> 4, c = lane & 15;
  const int wr = wid >> 1, wc = wid & 1;  // wave = 64x32 subtile
  const int bm = blockIdx.x, bn = blockIdx.y;

  f32x4 acc[4][2] = {};

  const char* Ag = (const char*)(A + (size_t)bm * 128 * K);
  const char* Bg = (const char*)(Bt + (size_t)bn * 64 * K);
  const int s0 = tid, s1 = tid + 256;
  const int ra0 = s0 >> 2, ca0 = (s0 & 3) * 16;
  const int ra1 = s1 >> 2, ca1 = (s1 & 3) * 16;
  const int rb = tid >> 2, cb2 = (tid & 3) * 16;
  const size_t rowbytes = (size_t)K * 2;

  auto stage = [&](int kt, int bufi) {
    const size_t koff = (size_t)kt * 64;  // 32 bf16 = 64B
    load16(Ag + (size_t)ra0 * rowbytes + koff + ca0, (char*)As[bufi] + s0 * 16);
    load16(Ag + (size_t)ra1 * rowbytes + koff + ca1, (char*)As[bufi] + s1 * 16);
    load16(Bg + (size_t)rb * rowbytes + koff + cb2, (char*)Bs[bufi] + tid * 16);
  };

  const int NT = K / 32;
  stage(0, 0);
  int cur = 0;
#pragma unroll 1
  for (int kt = 0; kt < NT; ++kt) {
    if (kt + 1 < NT) {
      stage(kt + 1, cur ^ 1);
      asm volatile("s_waitcnt vmcnt(3)" ::: "memory");  // own stage(kt) done
    } else {
      asm volatile("s_waitcnt vmcnt(0)" ::: "memory");
    }
    __builtin_amdgcn_s_barrier();

    bf16x8 af[4], bfr[2];
#pragma unroll
    for (int mi = 0; mi < 4; ++mi)
      af[mi] = *(const bf16x8*)&As[cur][(wr * 64 + mi * 16 + c) * 32 + g * 8];
#pragma unroll
    for (int ni = 0; ni < 2; ++ni)
      bfr[ni] = *(const bf16x8*)&Bs[cur][(wc * 32 + ni * 16 + c) * 32 + g * 8];
    __builtin_amdgcn_s_setprio(1);
#pragma unroll
    for (int mi = 0; mi < 4; ++mi)
#pragma unroll
      for (int ni = 0; ni < 2; ++ni)
        acc[mi][ni] = MFMA_BF16(af[mi], bfr[ni], acc[mi][ni]);
    __builtin_amdgcn_s_setprio(0);

    if (kt + 1 < NT) __builtin_amdgcn_s_barrier();
    cur ^= 1;
  }

#pragma unroll
  for (int ni = 0; ni < 2; ++ni) {
    const int n_g = bn * 64 + wc * 32 + ni * 16 + c;
    const float bv = bias[n_g];
#pragma unroll
    for (int mi = 0; mi < 4; ++mi) {
#pragma unroll
      for (int r = 0; r < 4; ++r) {
        const int m_g = bm * 128 + wr * 64 + mi * 16 + g * 4 + r;
        out[(size_t)m_g * DM_ + n_g] = acc[mi][ni][r] + bv;
      }
    }
  }
}

// ---------------- flash attention ----------------
// Q,K: (B,H,S,D) bf16 ; Vt: (B,H,D,S) bf16 ; Aout: (B,S,H*D) bf16
// Block = 4 waves = one t-quad of one bh; double-buffered XOR-swizzled LDS
// (R6-proven __syncthreads pipeline). Swapped-QK^T in-register softmax,
// defer-max gate on per-lane local max (R10), l via ones-MFMA (R12).
// R13 change (only): balanced quad->CU mapping. CU i serves locs
// {i, i+32, i+64, i+96} (one bh); map u=loc>>2 so each CU's 4 quads sum to
// 62 iters ({31-q, 16+q, 15-q, q}) instead of 76-4q (1.45x imbalance).
__global__ __launch_bounds__(256, 4) void flash_attn_kernel(
    const bf16* __restrict__ Q, const bf16* __restrict__ Kg,
    const bf16* __restrict__ Vt, bf16* __restrict__ Aout) {
  __shared__ bf16 Ks[2][64 * 64];
  __shared__ bf16 Vs[2][64 * 64];
  const int tid = threadIdx.x;
  const int w = tid >> 6, lane = tid & 63;
  const int g = lane >> 4, c = lane & 15;

  const int bid = blockIdx.x;
  const int xcd = bid & 7, loc = bid >> 3;
  const int bh = xcd * 4 + (loc & 3);
  const int u = loc >> 2;                 // 0..31
  const int slot = u >> 3, q = u & 7;
  const int j = slot == 0 ? 31 - q : slot == 1 ? 16 + q
              : slot == 2 ? 15 - q : q;   // balanced: per-CU sum = 62
  const int t = j * 4 + w;
  const int b = bh >> 4, h = bh & (H_ - 1);

  const float ALPHA2 = 0.125f * 1.44269504f;
  const float THR2 = 11.5f;
  const float NEG_INF = -__builtin_inff();

  const char* Kbase = (const char*)(Kg + (size_t)bh * S_ * D_);
  const char* Vbase = (const char*)(Vt + (size_t)bh * D_ * S_);
  const int s0 = tid, s1 = tid + 256;
  const int sr0 = s0 >> 3, sq0 = ((s0 & 7) ^ (sr0 & 7)) << 4;
  const int sr1 = s1 >> 3, sq1 = ((s1 & 7) ^ (sr1 & 7)) << 4;

  const bf16* Qp = Q + ((size_t)bh * S_ + t * 16 + c) * D_;
  bf16x8 qf[2];
  qf[0] = *(const bf16x8*)&Qp[g * 8];
  qf[1] = *(const bf16x8*)&Qp[32 + g * 8];

  bf16x8 onesf;
#pragma unroll
  for (int jj = 0; jj < 8; ++jj) onesf[jj] = (short)0x3f80;

  f32x4 o[4] = {};
  f32x4 lacc = {};
  float m = -1000.0f;

  const int rowlim = w * 16 + c;
  const int src0 = ((g & 1) * 2) * 16 + c;
  const int src1 = src0 + 16;
  const bool ghi = (g >= 2);
  const int cs = c & 7;
  int roff[2][4];
#pragma unroll
  for (int kk = 0; kk < 2; ++kk)
#pragma unroll
    for (int n = 0; n < 4; ++n)
      roff[kk][n] = n * 2048 + c * 128 + (((kk * 4 + g) ^ cs) << 4);

  {
    load16(Kbase + sr0 * 128 + sq0, (char*)Ks[0] + s0 * 16);
    load16(Kbase + sr1 * 128 + sq1, (char*)Ks[0] + s1 * 16);
    load16(Vbase + sr0 * 4096 + sq0, (char*)Vs[0] + s0 * 16);
    load16(Vbase + sr1 * 4096 + sq1, (char*)Vs[0] + s1 * 16);
  }
  __syncthreads();

  int cur = 0;
#pragma unroll 1
  for (int kv = 0; kv <= j; ++kv) {
    if (kv < j) {
      const char* Krow = Kbase + (size_t)(kv + 1) * 8192;
      const char* Vcol = Vbase + (size_t)(kv + 1) * 128;
      const int nb = cur ^ 1;
      load16(Krow + sr0 * 128 + sq0, (char*)Ks[nb] + s0 * 16);
      load16(Krow + sr1 * 128 + sq1, (char*)Ks[nb] + s1 * 16);
      load16(Vcol + sr0 * 4096 + sq0, (char*)Vs[nb] + s0 * 16);
      load16(Vcol + sr1 * 4096 + sq1, (char*)Vs[nb] + s1 * 16);
    }

    const char* Kt = (const char*)Ks[cur];
    const char* Vtile = (const char*)Vs[cur];
    bf16x8 kf[2][4];
#pragma unroll
    for (int kk = 0; kk < 2; ++kk)
#pragma unroll
      for (int n = 0; n < 4; ++n)
        kf[kk][n] = *(const bf16x8*)(Kt + roff[kk][n]);

    f32x4 st[4] = {};
    __builtin_amdgcn_s_setprio(1);
#pragma unroll
    for (int n = 0; n < 4; ++n) {
      st[n] = MFMA_BF16(kf[0][n], qf[0], st[n]);
      st[n] = MFMA_BF16(kf[1][n], qf[1], st[n]);
    }
    __builtin_amdgcn_s_setprio(0);

    bf16x8 vf[2][4];
#pragma unroll
    for (int kk = 0; kk < 2; ++kk)
#pragma unroll
      for (int n = 0; n < 4; ++n)
        vf[kk][n] = *(const bf16x8*)(Vtile + roff[kk][n]);

    float aa[4][4];
#pragma unroll
    for (int n = 0; n < 4; ++n)
#pragma unroll
      for (int r = 0; r < 4; ++r)
        aa[n][r] = fmaf(st[n][r], ALPHA2, -m);
    if (kv == j) {
#pragma unroll
      for (int n = 0; n < 4; ++n)
#pragma unroll
        for (int r = 0; r < 4; ++r)
          if (n * 16 + g * 4 + r > rowlim) aa[n][r] = NEG_INF;
    }

    float lm;
    {
      float t0 = fmaxf(fmaxf(aa[0][0], aa[0][1]), fmaxf(aa[0][2], aa[0][3]));
      float t1 = fmaxf(fmaxf(aa[1][0], aa[1][1]), fmaxf(aa[1][2], aa[1][3]));
      float t2 = fmaxf(fmaxf(aa[2][0], aa[2][1]), fmaxf(aa[2][2], aa[2][3]));
      float t3 = fmaxf(fmaxf(aa[3][0], aa[3][1]), fmaxf(aa[3][2], aa[3][3]));
      lm = fmaxf(fmaxf(t0, t1), fmaxf(t2, t3));
    }

    if (__any(lm > THR2)) {
      float dm = fmaxf(lm, __shfl_xor(lm, 16, 64));
      dm = fmaxf(dm, __shfl_xor(dm, 32, 64));
      const float sh = fmaxf(dm, 0.0f);
      const float sc = __builtin_amdgcn_exp2f(-sh);
      m += sh;
#pragma unroll
      for (int r = 0; r < 4; ++r) lacc[r] *= sc;
#pragma unroll
      for (int n = 0; n < 4; ++n)
#pragma unroll
        for (int r = 0; r < 4; ++r) o[n][r] *= sc;
#pragma unroll
      for (int n = 0; n < 4; ++n)
#pragma unroll
        for (int r = 0; r < 4; ++r) aa[n][r] -= sh;
    }

    float p[4][4];
#pragma unroll
    for (int n = 0; n < 4; ++n)
#pragma unroll
      for (int r = 0; r < 4; ++r) p[n][r] = __builtin_amdgcn_exp2f(aa[n][r]);

    unsigned int dw[4][2];
#pragma unroll
    for (int n = 0; n < 4; ++n) {
      dw[n][0] = pack_bf16(p[n][0], p[n][1]);
      dw[n][1] = pack_bf16(p[n][2], p[n][3]);
    }

#pragma unroll
    for (int kk = 0; kk < 2; ++kk) {
      unsigned int bb[4];
      {
        unsigned int lo = __shfl(dw[kk * 2][0], src0, 64);
        unsigned int hi = __shfl(dw[kk * 2 + 1][0], src0, 64);
        bb[0] = ghi ? hi : lo;
      }
      {
        unsigned int lo = __shfl(dw[kk * 2][1], src0, 64);
        unsigned int hi = __shfl(dw[kk * 2 + 1][1], src0, 64);
        bb[1] = ghi ? hi : lo;
      }
      {
        unsigned int lo = __shfl(dw[kk * 2][0], src1, 64);
        unsigned int hi = __shfl(dw[kk * 2 + 1][0], src1, 64);
        bb[2] = ghi ? hi : lo;
      }
      {
        unsigned int lo = __shfl(dw[kk * 2][1], src1, 64);
        unsigned int hi = __shfl(dw[kk * 2 + 1][1], src1, 64);
        bb[3] = ghi ? hi : lo;
      }
      u32x4 bbv = {bb[0], bb[1], bb[2], bb[3]};
      bf16x8 pb = __builtin_bit_cast(bf16x8, bbv);
      __builtin_amdgcn_s_setprio(1);
#pragma unroll
      for (int n = 0; n < 4; ++n) o[n] = MFMA_BF16(vf[kk][n], pb, o[n]);
      lacc = MFMA_BF16(onesf, pb, lacc);
      __builtin_amdgcn_s_setprio(0);
    }

    __syncthreads();
    cur ^= 1;
  }

  const float inv = 1.0f / lacc[0];

  bf16* Arow = Aout + ((size_t)b * S_ + t * 16 + c) * (H_ * D_) + h * D_;
#pragma unroll
  for (int n = 0; n < 4; ++n) {
    ushort4 u2;
    u2.x = __builtin_bit_cast(unsigned short, __float2bfloat16(o[n][0] * inv));
    u2.y = __builtin_bit_cast(unsigned short, __float2bfloat16(o[n][1] * inv));
    u2.z = __builtin_bit_cast(unsigned short, __float2bfloat16(o[n][2] * inv));
    u2.w = __builtin_bit_cast(unsigned short, __float2bfloat16(o[n][3] * inv));
    *(ushort4*)&Arow[n * 16 + g * 4] = u2;
  }
}

// ---------------- launcher ----------------

extern "C" void kernel_launch(void* const* d_in, const int* in_sizes, int n_in,
                              void* d_out, int out_size, void* d_ws, size_t ws_size,
                              hipStream_t stream) {
  (void)in_sizes; (void)n_in; (void)out_size; (void)ws_size;
  const float* x  = (const float*)d_in[0];
  const float* Wq = (const float*)d_in[1];
  const float* bq = (const float*)d_in[2];
  const float* Wk = (const float*)d_in[3];
  const float* bk = (const float*)d_in[4];
  const float* Wv = (const float*)d_in[5];
  const float* bv = (const float*)d_in[6];
  const float* Wo = (const float*)d_in[7];
  const float* bo = (const float*)d_in[8];
  float* out = (float*)d_out;

  char* ws = (char*)d_ws;
  bf16* xb  = (bf16*)(ws);                    // 8 MB  (4096x1024 bf16)
  bf16* Wqt = (bf16*)(ws + (8u << 20));       // 2 MB each, CONTIGUOUS (QKV fused)
  bf16* Wkt = (bf16*)(ws + (10u << 20));
  bf16* Wvt = (bf16*)(ws + (12u << 20));
  bf16* Wot = (bf16*)(ws + (14u << 20));
  bf16* Qb  = (bf16*)(ws + (16u << 20));      // 8 MB  (B,H,S,D)  -- +0*4194304
  bf16* Kb  = (bf16*)(ws + (24u << 20));      // 8 MB             -- +1*4194304
  bf16* Vtb = (bf16*)(ws + (32u << 20));      // 8 MB  (B,H,D,S)  -- +2*4194304
  bf16* Ab  = xb;  // attention out reuses xb (xb dead after projections)

  prep_kernel<<<dim3(32, 32, 5), 256, 0, stream>>>(
      Wq, Wk, Wv, Wo, x, Wqt, Wkt, Wvt, Wot, xb);

  // fused QKV projection: Bt = [Wqt;Wkt;Wvt] (3072 rows), 2-phase 128^2
  gemm_qkv_kernel<<<dim3(32, 24), 256, 0, stream>>>(
      xb, Wqt, bq, bk, bv, Qb, DM_);

  flash_attn_kernel<<<dim3(1024), 256, 0, stream>>>(Qb, Kb, Vtb, Ab);

  gemm_out_kernel<<<dim3(32, 16), 256, 0, stream>>>(Ab, Wot, bo, out, DM_);
}